// Round 3
// baseline (331.698 us; speedup 1.0000x reference)
//
#include <hip/hip_runtime.h>
#include <cstdint>
#include <cstddef>

#define B_ROWS 16384
#define D_DIM  1024
#define F_REAL 1034          // real hidden/feature dim
#define N_PAD  1152          // 9 * 128
#define K_PAD  1088          // 1024 h + 10 scal + 54 zero  (17 * 64)
#define NKT    34            // K-steps of BK=32
#define EPSN   1e-12f

typedef __bf16 bf16x8 __attribute__((ext_vector_type(8)));
typedef float  f32x4  __attribute__((ext_vector_type(4)));
typedef unsigned short u16;

__device__ __forceinline__ u16 f2bf(float f) {
    __bf16 b = (__bf16)f;
    return __builtin_bit_cast(u16, b);
}

// -------------------------------------------------------------------------
// prep (unchanged from R2): persistent waves, 4 rows/wave, depth-2 row
// pipeline. R0/R1/R2 all ~80us -> prep is L3-BW-bound (~2.9 TB/s serving
// the 190MB L3-resident inputs); restructuring can't move it.
// -------------------------------------------------------------------------
__global__ __launch_bounds__(256)
void prep_kernel(const float* __restrict__ h, const float* __restrict__ vp,
                 const float* __restrict__ vh, const float* __restrict__ nd,
                 const float* __restrict__ nsp, u16* __restrict__ A)
{
    const int tid  = threadIdx.x;
    const int lane = tid & 63;
    const int wg   = blockIdx.x * 4 + (tid >> 6);   // 0..4095
    const int r0   = wg * 4;

    const float4* ndp = (const float4*)nd;
    float4 n[4];
    #pragma unroll
    for (int c = 0; c < 4; ++c) n[c] = ndp[lane + c * 64];
    const float ns = nsp[0];

    float s_nn = 0.f;
    #pragma unroll
    for (int c = 0; c < 4; ++c)
        s_nn += n[c].x*n[c].x + n[c].y*n[c].y + n[c].z*n[c].z + n[c].w*n[c].w;
    #pragma unroll
    for (int m = 32; m >= 1; m >>= 1) s_nn += __shfl_xor(s_nn, m, 64);
    const float nnc = fmaxf(sqrtf(s_nn), EPSN);

    float4 P[2][4], Q[2][4], F[2][4];

#define LOADR(st, r)                                                          \
    do {                                                                      \
        const float4* vpp = (const float4*)(vp + (size_t)(r) * D_DIM);        \
        const float4* vhp = (const float4*)(vh + (size_t)(r) * D_DIM);        \
        const float4* hp  = (const float4*)(h  + (size_t)(r) * D_DIM);        \
        _Pragma("unroll")                                                     \
        for (int c = 0; c < 4; ++c) P[st][c] = vpp[lane + c * 64];            \
        _Pragma("unroll")                                                     \
        for (int c = 0; c < 4; ++c) Q[st][c] = vhp[lane + c * 64];            \
        _Pragma("unroll")                                                     \
        for (int c = 0; c < 4; ++c) F[st][c] = hp[lane + c * 64];             \
    } while (0)

    LOADR(0, r0);
    #pragma unroll
    for (int i = 0; i < 4; ++i) {
        const int st = i & 1;
        if (i + 1 < 4) LOADR(((i + 1) & 1), r0 + i + 1);
        __builtin_amdgcn_sched_barrier(0);   // keep next-row loads above use

        float s_pp = 0.f, s_hh = 0.f, s_pv = 0.f, s_ff = 0.f;
        float s_dd = 0.f, s_pn = 0.f, s_hn = 0.f;
        #pragma unroll
        for (int c = 0; c < 4; ++c) {
            float4 p = P[st][c], q = Q[st][c], f = F[st][c], nn = n[c];
            s_pp += p.x*p.x + p.y*p.y + p.z*p.z + p.w*p.w;
            s_hh += q.x*q.x + q.y*q.y + q.z*q.z + q.w*q.w;
            s_pv += p.x*q.x + p.y*q.y + p.z*q.z + p.w*q.w;
            s_ff += f.x*f.x + f.y*f.y + f.z*f.z + f.w*f.w;
            float dx = q.x-p.x, dy = q.y-p.y, dz = q.z-p.z, dw = q.w-p.w;
            s_dd += dx*dx + dy*dy + dz*dz + dw*dw;
            s_pn += p.x*nn.x + p.y*nn.y + p.z*nn.z + p.w*nn.w;
            s_hn += q.x*nn.x + q.y*nn.y + q.z*nn.z + q.w*nn.w;
        }

        u16* arow = A + (size_t)(r0 + i) * K_PAD;
        #pragma unroll
        for (int c = 0; c < 4; ++c) {
            ushort4 hc;
            hc.x = f2bf(F[st][c].x); hc.y = f2bf(F[st][c].y);
            hc.z = f2bf(F[st][c].z); hc.w = f2bf(F[st][c].w);
            *(ushort4*)(arow + (lane + c * 64) * 4) = hc;
        }

        #pragma unroll
        for (int m = 32; m >= 1; m >>= 1) {
            s_pp += __shfl_xor(s_pp, m, 64);
            s_hh += __shfl_xor(s_hh, m, 64);
            s_pv += __shfl_xor(s_pv, m, 64);
            s_ff += __shfl_xor(s_ff, m, 64);
            s_dd += __shfl_xor(s_dd, m, 64);
            s_pn += __shfl_xor(s_pn, m, 64);
            s_hn += __shfl_xor(s_hn, m, 64);
        }

        if (lane == 0) {
            float np_ = sqrtf(s_pp), nh_ = sqrtf(s_hh), nf = sqrtf(s_ff);
            float npc = fmaxf(np_, EPSN), nhc = fmaxf(nh_, EPSN);
            float align = s_pv / (npc * nhc);
            u16 fo[64];
            fo[0] = f2bf(align);
            fo[1] = f2bf(-align);
            fo[2] = f2bf(0.5f * (1.0f + align));      // K_O = 1
            fo[3] = f2bf(0.5f * (1.0f - align));
            fo[4] = f2bf(sqrtf(s_dd));
            fo[5] = f2bf(np_);
            fo[6] = f2bf(nh_);
            fo[7] = f2bf(nf);
            fo[8] = f2bf(ns * s_pn / (npc * nnc));
            fo[9] = f2bf(ns * s_hn / (nhc * nnc));
            #pragma unroll
            for (int k = 10; k < 64; ++k) fo[k] = 0;
            #pragma unroll
            for (int k = 0; k < 8; ++k)
                *(uint4*)(arow + D_DIM + k * 8) = *(uint4*)(fo + k * 8);
        }
    }
#undef LOADR
}

// -------------------------------------------------------------------------
// w1 [1034x1034] f32 -> padded bf16 B^T matrix [1152 x 1088]
// -------------------------------------------------------------------------
__global__ __launch_bounds__(256)
void convw_kernel(const float* __restrict__ w1, u16* __restrict__ Bm)
{
    const int i = blockIdx.x;
    for (int j = threadIdx.x; j < K_PAD; j += 256) {
        float v = (i < F_REAL && j < F_REAL) ? w1[(size_t)i * F_REAL + j] : 0.0f;
        Bm[(size_t)i * K_PAD + j] = f2bf(v);
    }
}

// out[b*3+c] = b2[c]  (out is poisoned 0xAA each launch)
__global__ __launch_bounds__(256)
void initout_kernel(const float* __restrict__ b2, float* __restrict__ out)
{
    int i = blockIdx.x * 256 + threadIdx.x;
    if (i < B_ROWS * 3) out[i] = b2[i % 3];
}

// -------------------------------------------------------------------------
// GEMM1 R3. Diagnosis R2: L3-BW-bound -- 9 bn-blocks re-fetch each A-panel
// from L3 (320MB at ~2.9TB/s ~= the 100us wall), plus drain-stall schedule.
// (a) XCD-aware bijective remap: xcd=flat%8, bm=xcd*16+k/9, bn=k%9 -> all
//     9 blocks sharing an A-panel run on ONE XCD; A fetched once from L3
//     (35.6MB), re-reads served by that XCD's L2 (panel+B ~ 5.5MB).
// (b) Counted vmcnt (T4): 3 LDS buffers (48KB -> 3 blocks/CU), prefetch
//     distance 2, raw "s_waitcnt vmcnt(4); s_barrier" per K-step (never
//     drain-0 in loop). Epilogue b1/w2 loads hoisted above first STAGE and
//     drained so in-loop vmcnt counts stay exact (4 loads per STAGE).
// (c) s_setprio(1) around the MFMA cluster.
// Same verified conflict-free swizzle + fused bias/ReLU/GEMM2 epilogue.
// -------------------------------------------------------------------------
__global__ __launch_bounds__(256)
void gemm_kernel(const u16* __restrict__ A,
                 const u16* __restrict__ Bm,
                 const float* __restrict__ b1, const float* __restrict__ w2,
                 float* __restrict__ out)
{
    __shared__ __bf16 As[3 * 128 * 32];   // 24 KB (3 buffers)
    __shared__ __bf16 Bs[3 * 128 * 32];   // 24 KB

    const int tid  = threadIdx.x;
    const int lane = tid & 63;
    const int wave = tid >> 6;
    const int wm = wave >> 1, wn = wave & 1;   // wave covers 64(m) x 64(n)

    // XCD-aware bijective remap: 1152 = 8 xcd * (16 bm * 9 bn)
    const int flat = blockIdx.x;
    const int xcd  = flat & 7;
    const int kk   = flat >> 3;          // 0..143
    const int bm   = xcd * 16 + kk / 9;
    const int bn   = kk % 9;

    // staging: slot s = l*256 + tid; row = s>>2; src chunk = (s&3)^((row>>1)&3)
    const u16* srcA[2];
    const u16* srcB[2];
    #pragma unroll
    for (int l = 0; l < 2; ++l) {
        int s   = l * 256 + tid;
        int row = s >> 2;
        int c   = (s & 3) ^ ((s >> 3) & 3);
        srcA[l] = A  + (size_t)(bm * 128 + row) * K_PAD + c * 8;
        srcB[l] = Bm + (size_t)(bn * 128 + row) * K_PAD + c * 8;
    }
    const int ldsbase = wave * 512;   // wave-uniform element base (+l*2048)

#define STAGE(buf, kt)                                                        \
    do {                                                                      \
        _Pragma("unroll")                                                     \
        for (int l = 0; l < 2; ++l) {                                         \
            __builtin_amdgcn_global_load_lds(                                 \
                (const __attribute__((address_space(1))) void*)(srcA[l] + (kt) * 32), \
                (__attribute__((address_space(3))) void*)(As + (buf) * 4096 + l * 2048 + ldsbase), \
                16, 0, 0);                                                    \
            __builtin_amdgcn_global_load_lds(                                 \
                (const __attribute__((address_space(1))) void*)(srcB[l] + (kt) * 32), \
                (__attribute__((address_space(3))) void*)(Bs + (buf) * 4096 + l * 2048 + ldsbase), \
                16, 0, 0);                                                    \
        }                                                                     \
    } while (0)

    const int col  = lane & 15;
    const int quad = lane >> 4;
    const int swz  = quad ^ ((col >> 1) & 3);
    int aoff[4], boff[4];
    #pragma unroll
    for (int i = 0; i < 4; ++i)
        aoff[i] = (wm * 64 + i * 16 + col) * 32 + swz * 8;
    #pragma unroll
    for (int j = 0; j < 4; ++j)
        boff[j] = (wn * 64 + j * 16 + col) * 32 + swz * 8;

    f32x4 acc[4][4];
    #pragma unroll
    for (int i = 0; i < 4; ++i)
        #pragma unroll
        for (int j = 0; j < 4; ++j)
            acc[i][j] = (f32x4){0.f, 0.f, 0.f, 0.f};

#define COMPUTE(buf)                                                          \
    do {                                                                      \
        const __bf16* Ab = As + (buf) * 4096;                                 \
        const __bf16* Bb = Bs + (buf) * 4096;                                 \
        bf16x8 av[4], bv[4];                                                  \
        _Pragma("unroll")                                                     \
        for (int i = 0; i < 4; ++i) av[i] = *(const bf16x8*)(Ab + aoff[i]);   \
        _Pragma("unroll")                                                     \
        for (int j = 0; j < 4; ++j) bv[j] = *(const bf16x8*)(Bb + boff[j]);   \
        _Pragma("unroll")                                                     \
        for (int i = 0; i < 4; ++i)                                           \
            _Pragma("unroll")                                                 \
            for (int j = 0; j < 4; ++j)                                       \
                acc[i][j] = __builtin_amdgcn_mfma_f32_16x16x32_bf16(          \
                                av[i], bv[j], acc[i][j], 0, 0, 0);            \
    } while (0)

    // epilogue params loaded FIRST and drained, so in-loop vmcnt counts
    // only tile loads (4 global_load_lds per STAGE).
    float bias[4], w20[4], w21[4], w22[4];
    #pragma unroll
    for (int ni = 0; ni < 4; ++ni) {
        int n = bn * 128 + wn * 64 + ni * 16 + col;
        bool v = n < F_REAL;   // padded rows have acc==0 anyway
        bias[ni] = v ? b1[n] : 0.0f;
        w20[ni]  = v ? w2[n] : 0.0f;
        w21[ni]  = v ? w2[F_REAL + n] : 0.0f;
        w22[ni]  = v ? w2[2 * F_REAL + n] : 0.0f;
    }
    asm volatile("s_waitcnt vmcnt(0)" ::: "memory");
    __builtin_amdgcn_sched_barrier(0);

    // prologue: tiles 0,1 in flight
    STAGE(0, 0);
    STAGE(1, 1);

    int cb = 0;                               // buffer holding tile t
    for (int t = 0; t < NKT - 1; ++t) {
        // own tile-t loads done once <=4 newer (tile t+1) remain in flight
        asm volatile("s_waitcnt vmcnt(4)\n\ts_barrier" ::: "memory");
        __builtin_amdgcn_sched_barrier(0);
        if (t + 2 < NKT) {
            int nb = cb + 2; if (nb >= 3) nb -= 3;
            STAGE(nb, t + 2);
        }
        __builtin_amdgcn_s_setprio(1);
        COMPUTE(cb);
        __builtin_amdgcn_s_setprio(0);
        if (++cb == 3) cb = 0;
    }
    asm volatile("s_waitcnt vmcnt(0)\n\ts_barrier" ::: "memory");
    __builtin_amdgcn_sched_barrier(0);
    __builtin_amdgcn_s_setprio(1);
    COMPUTE(cb);
    __builtin_amdgcn_s_setprio(0);

    // epilogue: hidden = relu(acc + b1[n]); logits partial = hidden @ w2^T
    #pragma unroll
    for (int mi = 0; mi < 4; ++mi) {
        float c0[4] = {0,0,0,0}, c1[4] = {0,0,0,0}, c2[4] = {0,0,0,0};
        #pragma unroll
        for (int ni = 0; ni < 4; ++ni) {
            #pragma unroll
            for (int r = 0; r < 4; ++r) {
                float hd = fmaxf(acc[mi][ni][r] + bias[ni], 0.0f);
                c0[r] += hd * w20[ni];
                c1[r] += hd * w21[ni];
                c2[r] += hd * w22[ni];
            }
        }
        #pragma unroll
        for (int m = 8; m >= 1; m >>= 1) {
            #pragma unroll
            for (int r = 0; r < 4; ++r) {
                c0[r] += __shfl_xor(c0[r], m, 64);
                c1[r] += __shfl_xor(c1[r], m, 64);
                c2[r] += __shfl_xor(c2[r], m, 64);
            }
        }
        if (col == 0) {
            int gm = bm * 128 + wm * 64 + mi * 16 + quad * 4;
            #pragma unroll
            for (int r = 0; r < 4; ++r) {
                atomicAdd(out + (size_t)(gm + r) * 3 + 0, c0[r]);
                atomicAdd(out + (size_t)(gm + r) * 3 + 1, c1[r]);
                atomicAdd(out + (size_t)(gm + r) * 3 + 2, c2[r]);
            }
        }
    }
#undef STAGE
#undef COMPUTE
}

extern "C" void kernel_launch(void* const* d_in, const int* in_sizes, int n_in,
                              void* d_out, int out_size, void* d_ws, size_t ws_size,
                              hipStream_t stream)
{
    const float* h  = (const float*)d_in[0];
    const float* vp = (const float*)d_in[1];
    const float* vh = (const float*)d_in[2];
    const float* nd = (const float*)d_in[3];
    const float* ns = (const float*)d_in[4];
    const float* w1 = (const float*)d_in[5];
    const float* b1 = (const float*)d_in[6];
    const float* w2 = (const float*)d_in[7];
    const float* b2 = (const float*)d_in[8];
    float* out = (float*)d_out;

    u16* Afull = (u16*)d_ws;                              // [16384][1088] bf16
    u16* Bfull = Afull + (size_t)B_ROWS * K_PAD;          // [1152][1088]  bf16

    prep_kernel<<<1024, 256, 0, stream>>>(h, vp, vh, nd, ns, Afull);
    convw_kernel<<<N_PAD, 256, 0, stream>>>(w1, Bfull);
    initout_kernel<<<(B_ROWS * 3 + 255) / 256, 256, 0, stream>>>(b2, out);
    gemm_kernel<<<B_ROWS / 128 * (N_PAD / 128), 256, 0, stream>>>(
        Afull, Bfull, b1, w2, out);
}

// Round 5
// 289.981 us; speedup vs baseline: 1.1439x; 1.1439x over previous
//
#include <hip/hip_runtime.h>
#include <cstdint>
#include <cstddef>

#define B_ROWS 16384
#define D_DIM  1024
#define F_REAL 1034          // real hidden/feature dim
#define N_PAD  1152          // 9 * 128
#define K_PAD  1088          // 1024 h + 10 scal + 54 zero  (17 * 64)
#define NK     (K_PAD / 64)  // 17 iterations of BK=64
#define EPSN   1e-12f

typedef __bf16 bf16x8 __attribute__((ext_vector_type(8)));
typedef float  f32x4  __attribute__((ext_vector_type(4)));
typedef unsigned short u16;

__device__ __forceinline__ u16 f2bf(float f) {
    __bf16 b = (__bf16)f;
    return __builtin_bit_cast(u16, b);
}

// -------------------------------------------------------------------------
// prep (R3 version, kept): persistent waves, 4 rows/wave, depth-2 row
// pipeline, nd/s_nn hoisted. Inferred ~71us (below gemm in top-5).
// -------------------------------------------------------------------------
__global__ __launch_bounds__(256)
void prep_kernel(const float* __restrict__ h, const float* __restrict__ vp,
                 const float* __restrict__ vh, const float* __restrict__ nd,
                 const float* __restrict__ nsp, u16* __restrict__ A)
{
    const int tid  = threadIdx.x;
    const int lane = tid & 63;
    const int wg   = blockIdx.x * 4 + (tid >> 6);   // 0..4095
    const int r0   = wg * 4;

    const float4* ndp = (const float4*)nd;
    float4 n[4];
    #pragma unroll
    for (int c = 0; c < 4; ++c) n[c] = ndp[lane + c * 64];
    const float ns = nsp[0];

    float s_nn = 0.f;
    #pragma unroll
    for (int c = 0; c < 4; ++c)
        s_nn += n[c].x*n[c].x + n[c].y*n[c].y + n[c].z*n[c].z + n[c].w*n[c].w;
    #pragma unroll
    for (int m = 32; m >= 1; m >>= 1) s_nn += __shfl_xor(s_nn, m, 64);
    const float nnc = fmaxf(sqrtf(s_nn), EPSN);

    float4 P[2][4], Q[2][4], F[2][4];

#define LOADR(st, r)                                                          \
    do {                                                                      \
        const float4* vpp = (const float4*)(vp + (size_t)(r) * D_DIM);        \
        const float4* vhp = (const float4*)(vh + (size_t)(r) * D_DIM);        \
        const float4* hp  = (const float4*)(h  + (size_t)(r) * D_DIM);        \
        _Pragma("unroll")                                                     \
        for (int c = 0; c < 4; ++c) P[st][c] = vpp[lane + c * 64];            \
        _Pragma("unroll")                                                     \
        for (int c = 0; c < 4; ++c) Q[st][c] = vhp[lane + c * 64];            \
        _Pragma("unroll")                                                     \
        for (int c = 0; c < 4; ++c) F[st][c] = hp[lane + c * 64];             \
    } while (0)

    LOADR(0, r0);
    #pragma unroll
    for (int i = 0; i < 4; ++i) {
        const int st = i & 1;
        if (i + 1 < 4) LOADR(((i + 1) & 1), r0 + i + 1);
        __builtin_amdgcn_sched_barrier(0);   // keep next-row loads above use

        float s_pp = 0.f, s_hh = 0.f, s_pv = 0.f, s_ff = 0.f;
        float s_dd = 0.f, s_pn = 0.f, s_hn = 0.f;
        #pragma unroll
        for (int c = 0; c < 4; ++c) {
            float4 p = P[st][c], q = Q[st][c], f = F[st][c], nn = n[c];
            s_pp += p.x*p.x + p.y*p.y + p.z*p.z + p.w*p.w;
            s_hh += q.x*q.x + q.y*q.y + q.z*q.z + q.w*q.w;
            s_pv += p.x*q.x + p.y*q.y + p.z*q.z + p.w*q.w;
            s_ff += f.x*f.x + f.y*f.y + f.z*f.z + f.w*f.w;
            float dx = q.x-p.x, dy = q.y-p.y, dz = q.z-p.z, dw = q.w-p.w;
            s_dd += dx*dx + dy*dy + dz*dz + dw*dw;
            s_pn += p.x*nn.x + p.y*nn.y + p.z*nn.z + p.w*nn.w;
            s_hn += q.x*nn.x + q.y*nn.y + q.z*nn.z + q.w*nn.w;
        }

        u16* arow = A + (size_t)(r0 + i) * K_PAD;
        #pragma unroll
        for (int c = 0; c < 4; ++c) {
            ushort4 hc;
            hc.x = f2bf(F[st][c].x); hc.y = f2bf(F[st][c].y);
            hc.z = f2bf(F[st][c].z); hc.w = f2bf(F[st][c].w);
            *(ushort4*)(arow + (lane + c * 64) * 4) = hc;
        }

        #pragma unroll
        for (int m = 32; m >= 1; m >>= 1) {
            s_pp += __shfl_xor(s_pp, m, 64);
            s_hh += __shfl_xor(s_hh, m, 64);
            s_pv += __shfl_xor(s_pv, m, 64);
            s_ff += __shfl_xor(s_ff, m, 64);
            s_dd += __shfl_xor(s_dd, m, 64);
            s_pn += __shfl_xor(s_pn, m, 64);
            s_hn += __shfl_xor(s_hn, m, 64);
        }

        if (lane == 0) {
            float np_ = sqrtf(s_pp), nh_ = sqrtf(s_hh), nf = sqrtf(s_ff);
            float npc = fmaxf(np_, EPSN), nhc = fmaxf(nh_, EPSN);
            float align = s_pv / (npc * nhc);
            u16 fo[64];
            fo[0] = f2bf(align);
            fo[1] = f2bf(-align);
            fo[2] = f2bf(0.5f * (1.0f + align));      // K_O = 1
            fo[3] = f2bf(0.5f * (1.0f - align));
            fo[4] = f2bf(sqrtf(s_dd));
            fo[5] = f2bf(np_);
            fo[6] = f2bf(nh_);
            fo[7] = f2bf(nf);
            fo[8] = f2bf(ns * s_pn / (npc * nnc));
            fo[9] = f2bf(ns * s_hn / (nhc * nnc));
            #pragma unroll
            for (int k = 10; k < 64; ++k) fo[k] = 0;
            #pragma unroll
            for (int k = 0; k < 8; ++k)
                *(uint4*)(arow + D_DIM + k * 8) = *(uint4*)(fo + k * 8);
        }
    }
#undef LOADR
}

// -------------------------------------------------------------------------
// w1 [1034x1034] f32 -> padded bf16 B^T [1152 x 1088]; initout folded in
// (blocks < 192 also write out = b2 broadcast) -- saves one launch.
// -------------------------------------------------------------------------
__global__ __launch_bounds__(256)
void convw_kernel(const float* __restrict__ w1, u16* __restrict__ Bm,
                  const float* __restrict__ b2, float* __restrict__ out)
{
    const int i = blockIdx.x;
    for (int j = threadIdx.x; j < K_PAD; j += 256) {
        float v = (i < F_REAL && j < F_REAL) ? w1[(size_t)i * F_REAL + j] : 0.0f;
        Bm[(size_t)i * K_PAD + j] = f2bf(v);
    }
    if (i < 192) {                      // 192*256 == 16384*3
        int o = i * 256 + threadIdx.x;
        out[o] = b2[o % 3];
    }
}

// -------------------------------------------------------------------------
// GEMM1 R4: EXACT R0 structure (measured best, 80.5us: 64x128 tile, BK=64,
// depth-2 REGISTER pipeline, 2 barriers/K-tile, bm-fastest 2304-block grid)
// with ONE change: the swizzle. R0's quad^(col&3) degenerates per 8-lane
// LDS processing group to 4*(col&1)+quad -> 4-way conflict (7.52M measured).
// quad^((col>>1)&3) measured ZERO conflicts in R1/R2/R3. Store-side chunk
// select changed to match: (s&3)^((s>>3)&3).
// R1-R3 lesson: this kernel is latency/barrier-bound; many small blocks
// (2304) overlapping stalls beat bigger tiles / deeper pipelines.
// -------------------------------------------------------------------------
__global__ __launch_bounds__(256)
void gemm_kernel(const u16* __restrict__ A,
                 const u16* __restrict__ Bm,
                 const float* __restrict__ b1, const float* __restrict__ w2,
                 float* __restrict__ out)
{
    // two 32-k halves; slot layout (row*4 + (kc^((row>>1)&3)))*8
    __shared__ __bf16 As[2 * 64 * 32];    // 8 KB
    __shared__ __bf16 Bs[2 * 128 * 32];   // 16 KB

    const int tid  = threadIdx.x;
    const int lane = tid & 63;
    const int wave = tid >> 6;
    const int wm = wave >> 1, wn = wave & 1;   // wave covers 32(m) x 64(n)
    const int bm = blockIdx.x, bn = blockIdx.y;

    const u16* gaA;
    __bf16*    lA;
    {
        int row = tid >> 2;
        int kc  = (tid & 3) ^ ((tid >> 3) & 3);     // zero-conflict swizzle
        gaA = A + (size_t)(bm * 64 + row) * K_PAD + kc * 8;
        lA  = As + tid * 8;
    }
    const u16* gaB[2];
    __bf16*    lB[2];
    #pragma unroll
    for (int o = 0; o < 2; ++o) {
        int s   = o * 256 + tid;
        int row = s >> 2;
        int kc  = (s & 3) ^ ((s >> 3) & 3);         // zero-conflict swizzle
        gaB[o] = Bm + (size_t)(bn * 128 + row) * K_PAD + kc * 8;
        lB[o]  = Bs + s * 8;
    }

    const int col  = lane & 15;
    const int quad = lane >> 4;
    const int swz  = quad ^ ((col >> 1) & 3);       // zero-conflict swizzle
    int aoff[2], boff[4];
    #pragma unroll
    for (int i = 0; i < 2; ++i)
        aoff[i] = ((wm * 32 + i * 16 + col) * 4 + swz) * 8;
    #pragma unroll
    for (int j = 0; j < 4; ++j)
        boff[j] = ((wn * 64 + j * 16 + col) * 4 + swz) * 8;

    f32x4 acc[2][4];
    #pragma unroll
    for (int i = 0; i < 2; ++i)
        #pragma unroll
        for (int j = 0; j < 4; ++j)
            acc[i][j] = (f32x4){0.f, 0.f, 0.f, 0.f};

    // two register stages; tile t lives in stage t&1
    uint4 a0_0, a1_0, b00_0, b01_0, b10_0, b11_0;
    uint4 a0_1, a1_1, b00_1, b01_1, b10_1, b11_1;

#define LOAD_STAGE(st, ko)                                                    \
    do {                                                                      \
        a0_##st  = *(const uint4*)(gaA + (ko));                               \
        a1_##st  = *(const uint4*)(gaA + (ko) + 32);                          \
        b00_##st = *(const uint4*)(gaB[0] + (ko));                            \
        b01_##st = *(const uint4*)(gaB[0] + (ko) + 32);                       \
        b10_##st = *(const uint4*)(gaB[1] + (ko));                            \
        b11_##st = *(const uint4*)(gaB[1] + (ko) + 32);                       \
    } while (0)

#define WRITE_STAGE(st)                                                       \
    do {                                                                      \
        *(uint4*)(lA)           = a0_##st;                                    \
        *(uint4*)(lA + 2048)    = a1_##st;                                    \
        *(uint4*)(lB[0])        = b00_##st;                                   \
        *(uint4*)(lB[0] + 4096) = b01_##st;                                   \
        *(uint4*)(lB[1])        = b10_##st;                                   \
        *(uint4*)(lB[1] + 4096) = b11_##st;                                   \
    } while (0)

#define COMPUTE_TILE                                                          \
    do {                                                                      \
        _Pragma("unroll")                                                     \
        for (int h = 0; h < 2; ++h) {                                         \
            const __bf16* Ab = As + h * 2048;                                 \
            const __bf16* Bb = Bs + h * 4096;                                 \
            bf16x8 av[2], bv[4];                                              \
            _Pragma("unroll")                                                 \
            for (int i = 0; i < 2; ++i) av[i] = *(const bf16x8*)(Ab + aoff[i]); \
            _Pragma("unroll")                                                 \
            for (int j = 0; j < 4; ++j) bv[j] = *(const bf16x8*)(Bb + boff[j]); \
            _Pragma("unroll")                                                 \
            for (int i = 0; i < 2; ++i)                                       \
                _Pragma("unroll")                                             \
                for (int j = 0; j < 4; ++j)                                   \
                    acc[i][j] = __builtin_amdgcn_mfma_f32_16x16x32_bf16(      \
                                    av[i], bv[j], acc[i][j], 0, 0, 0);        \
        }                                                                     \
    } while (0)

    // prologue: t0 -> S0, t1 -> S1 (both in flight), write t0, sync
    LOAD_STAGE(0, 0);
    LOAD_STAGE(1, 64);
    WRITE_STAGE(0);
    __syncthreads();

    for (int kt = 0; kt < NK; kt += 2) {
        // even sub-iter kt: prefetch t(kt+2) -> S0; write t(kt+1) from S1
        if (kt + 2 < NK) LOAD_STAGE(0, (kt + 2) * 64);
        COMPUTE_TILE;
        if (kt + 1 < NK) {
            __syncthreads();
            WRITE_STAGE(1);
            __syncthreads();

            // odd sub-iter kt+1: prefetch t(kt+3) -> S1; write t(kt+2) from S0
            if (kt + 3 < NK) LOAD_STAGE(1, (kt + 3) * 64);
            COMPUTE_TILE;
            if (kt + 2 < NK) {
                __syncthreads();
                WRITE_STAGE(0);
                __syncthreads();
            }
        }
    }

    // epilogue: hidden = relu(acc + b1[n]); logits partial = hidden @ w2^T
    float bias[4], w20[4], w21[4], w22[4];
    #pragma unroll
    for (int ni = 0; ni < 4; ++ni) {
        int n = bn * 128 + wn * 64 + ni * 16 + col;
        bool v = n < F_REAL;   // padded rows have acc==0 anyway
        bias[ni] = v ? b1[n] : 0.0f;
        w20[ni]  = v ? w2[n] : 0.0f;
        w21[ni]  = v ? w2[F_REAL + n] : 0.0f;
        w22[ni]  = v ? w2[2 * F_REAL + n] : 0.0f;
    }
    #pragma unroll
    for (int mi = 0; mi < 2; ++mi) {
        float c0[4] = {0,0,0,0}, c1[4] = {0,0,0,0}, c2[4] = {0,0,0,0};
        #pragma unroll
        for (int ni = 0; ni < 4; ++ni) {
            #pragma unroll
            for (int r = 0; r < 4; ++r) {
                float hd = fmaxf(acc[mi][ni][r] + bias[ni], 0.0f);
                c0[r] += hd * w20[ni];
                c1[r] += hd * w21[ni];
                c2[r] += hd * w22[ni];
            }
        }
        #pragma unroll
        for (int m = 8; m >= 1; m >>= 1) {
            #pragma unroll
            for (int r = 0; r < 4; ++r) {
                c0[r] += __shfl_xor(c0[r], m, 64);
                c1[r] += __shfl_xor(c1[r], m, 64);
                c2[r] += __shfl_xor(c2[r], m, 64);
            }
        }
        if (col == 0) {
            int gm = bm * 64 + wm * 32 + mi * 16 + quad * 4;
            #pragma unroll
            for (int r = 0; r < 4; ++r) {
                atomicAdd(out + (size_t)(gm + r) * 3 + 0, c0[r]);
                atomicAdd(out + (size_t)(gm + r) * 3 + 1, c1[r]);
                atomicAdd(out + (size_t)(gm + r) * 3 + 2, c2[r]);
            }
        }
    }
#undef LOAD_STAGE
#undef WRITE_STAGE
#undef COMPUTE_TILE
}

extern "C" void kernel_launch(void* const* d_in, const int* in_sizes, int n_in,
                              void* d_out, int out_size, void* d_ws, size_t ws_size,
                              hipStream_t stream)
{
    const float* h  = (const float*)d_in[0];
    const float* vp = (const float*)d_in[1];
    const float* vh = (const float*)d_in[2];
    const float* nd = (const float*)d_in[3];
    const float* ns = (const float*)d_in[4];
    const float* w1 = (const float*)d_in[5];
    const float* b1 = (const float*)d_in[6];
    const float* w2 = (const float*)d_in[7];
    const float* b2 = (const float*)d_in[8];
    float* out = (float*)d_out;

    u16* Afull = (u16*)d_ws;                              // [16384][1088] bf16
    u16* Bfull = Afull + (size_t)B_ROWS * K_PAD;          // [1152][1088]  bf16

    prep_kernel<<<1024, 256, 0, stream>>>(h, vp, vh, nd, ns, Afull);
    convw_kernel<<<N_PAD, 256, 0, stream>>>(w1, Bfull, b2, out);
    gemm_kernel<<<dim3(B_ROWS / 64, N_PAD / 128), 256, 0, stream>>>(
        Afull, Bfull, b1, w2, out);
}